// Round 1
// baseline (190.475 us; speedup 1.0000x reference)
//
#include <hip/hip_runtime.h>
#include <hip/hip_fp16.h>
#include <math.h>

typedef _Float16 half8 __attribute__((ext_vector_type(8)));
typedef float floatx4 __attribute__((ext_vector_type(4)));

#define BB 32
#define SS 48
#define LL 64
#define FF 256

// ---- prep (proven): W1 -> fp16 hi/lo MFMA-B fragment order ----
//   flat = ((kt*16 + nt)*64 + lane)*8 + j ; element = W1[kt*32+(lane>>4)*8+j][nt*16+(lane&15)]
__global__ __launch_bounds__(256) void prep_w(const float* __restrict__ W1,
                                              _Float16* __restrict__ whi,
                                              _Float16* __restrict__ wlo) {
    int idx = blockIdx.x * 256 + threadIdx.x;
    int j    = idx & 7;
    int lane = (idx >> 3) & 63;
    int nt   = (idx >> 9) & 15;
    int kt   = idx >> 13;
    int k = kt * 32 + ((lane >> 4) & 3) * 8 + j;
    int n = nt * 16 + (lane & 15);
    float x = W1[k * FF + n];
    _Float16 hi = (_Float16)x;
    _Float16 lo = (_Float16)(x - (float)hi);
    whi[idx] = hi;
    wlo[idx] = lo;
}

// ---- fused kernel: 8-wave / 512-thread occupancy restructure ----
// Wave w owns output cols [32w, 32w+32): acc[4][2] = 32 AGPRs (was 64).
// B fragments streamed per-ktl from L2-hot whi/wlo with 1-deep prefetch
// (32 VGPRs, was 128 preloaded). Two-half peeled A staging kept verbatim,
// rescaled: a1raw = 16 VGPRs (was 32). Target <=128 total regs ->
// 2 blocks/CU = 16 waves/CU (50% occupancy ceiling, was 25%).
__global__ __launch_bounds__(512, 4) void ida_mfma(
    const float* __restrict__ features,
    const float* __restrict__ src_locs,
    const float* __restrict__ tar_locs,
    const _Float16* __restrict__ whi,
    const _Float16* __restrict__ wlo,
    const float* __restrict__ b1,
    const float* __restrict__ W2,
    const float* __restrict__ b2,
    float* __restrict__ out)
{
    __shared__ _Float16 Ahi[8192];   // 16 KiB: [(mt*4+ktl)*64 + lane]*8
    __shared__ _Float16 Alo[8192];   // 16 KiB
    __shared__ float SP[LL * 8];     // layer-2 partials [row][wave]  (2 KiB)
    __shared__ float wbuf[LL];       // softmax weights
    __shared__ float red[8 * FF];    // weighted-sum cross-wave reduce (8 KiB)

    const int t    = threadIdx.x;
    const int w    = t >> 6;         // wave 0..7 -> owns cols 32w..32w+31
    const int lane = t & 63;
    const int quad = lane >> 4;
    const int l16  = lane & 15;
    const int bs   = blockIdx.x;
    const int b    = bs / SS;

    const float* Xg = features + (size_t)bs * (LL * FF);

    floatx4 acc[4][2] = {};          // [mt][ntl] -> 32 AGPRs
    half8 bh[2], bl[2], nbh[2], nbl[2];

    // ---- stage half 0 (A0: global load + cvt + ds_write) ----
    // group g = it*8+w (0..15): row=(g>>2)*16+l16, kcol=(g&3)*32+quad*8
    #pragma unroll
    for (int it = 0; it < 2; ++it) {
        int g   = it * 8 + w;
        int row = (g >> 2) * 16 + l16;
        int kc  = (g & 3) * 32 + quad * 8;
        const float4* p = (const float4*)(Xg + row * FF + kc);
        float4 x0 = p[0], x1 = p[1];
        float xs[8] = {x0.x, x0.y, x0.z, x0.w, x1.x, x1.y, x1.z, x1.w};
        half8 hi, lo;
        #pragma unroll
        for (int j = 0; j < 8; ++j) {
            _Float16 h = (_Float16)xs[j];
            hi[j] = h;
            lo[j] = (_Float16)(xs[j] - (float)h);
        }
        *((half8*)&Ahi[(g * 64 + lane) * 8]) = hi;
        *((half8*)&Alo[(g * 64 + lane) * 8]) = lo;
    }

    // ---- issue A1 raw loads now; latency hides under half-0 compute ----
    float4 a1raw[4];
    #pragma unroll
    for (int it = 0; it < 2; ++it) {
        int g   = it * 8 + w;
        int row = (g >> 2) * 16 + l16;
        int kc  = (g & 3) * 32 + quad * 8;
        const float4* p = (const float4*)(Xg + row * FF + 128 + kc);
        a1raw[2 * it + 0] = p[0];
        a1raw[2 * it + 1] = p[1];
    }

    // ---- preload B fragments for half 0, ktl 0 ----
    #pragma unroll
    for (int ntl = 0; ntl < 2; ++ntl) {
        size_t off = ((size_t)(0 * 16 + (w * 2 + ntl)) * 64 + lane) * 8;
        bh[ntl] = *((const half8*)(whi + off));
        bl[ntl] = *((const half8*)(wlo + off));
    }

    __syncthreads();

    // ---- compute one K-half: per-ktl B prefetch + MFMA ----
#define COMPUTE_HALF(h)                                                          \
    _Pragma("unroll")                                                            \
    for (int ktl = 0; ktl < 4; ++ktl) {                                          \
        if (ktl < 3) {                                                           \
            _Pragma("unroll")                                                    \
            for (int ntl = 0; ntl < 2; ++ntl) {                                  \
                size_t off = ((size_t)(((h) * 4 + ktl + 1) * 16 + (w * 2 + ntl)) * 64 + lane) * 8; \
                nbh[ntl] = *((const half8*)(whi + off));                         \
                nbl[ntl] = *((const half8*)(wlo + off));                         \
            }                                                                    \
        }                                                                        \
        _Pragma("unroll")                                                        \
        for (int mt = 0; mt < 4; ++mt) {                                         \
            half8 ahi = *((half8*)&Ahi[((mt * 4 + ktl) * 64 + lane) * 8]);       \
            half8 alo = *((half8*)&Alo[((mt * 4 + ktl) * 64 + lane) * 8]);       \
            _Pragma("unroll")                                                    \
            for (int ntl = 0; ntl < 2; ++ntl) {                                  \
                acc[mt][ntl] = __builtin_amdgcn_mfma_f32_16x16x32_f16(ahi, bh[ntl], acc[mt][ntl], 0, 0, 0); \
                acc[mt][ntl] = __builtin_amdgcn_mfma_f32_16x16x32_f16(ahi, bl[ntl], acc[mt][ntl], 0, 0, 0); \
                acc[mt][ntl] = __builtin_amdgcn_mfma_f32_16x16x32_f16(alo, bh[ntl], acc[mt][ntl], 0, 0, 0); \
            }                                                                    \
        }                                                                        \
        if (ktl < 3) {                                                           \
            bh[0] = nbh[0]; bh[1] = nbh[1];                                      \
            bl[0] = nbl[0]; bl[1] = nbl[1];                                      \
        }                                                                        \
    }

    // ---- compute half 0 ----
    COMPUTE_HALF(0)

    // ---- preload B for half 1, ktl 0 (hides under stage1, no global wait there) ----
    #pragma unroll
    for (int ntl = 0; ntl < 2; ++ntl) {
        size_t off = ((size_t)(4 * 16 + (w * 2 + ntl)) * 64 + lane) * 8;
        bh[ntl] = *((const half8*)(whi + off));
        bl[ntl] = *((const half8*)(wlo + off));
    }

    __syncthreads();   // half-0 LDS reads complete before overwrite

    // ---- stage half 1 (cvt + ds_write only; a1raw long in flight) ----
    #pragma unroll
    for (int it = 0; it < 2; ++it) {
        int g = it * 8 + w;
        float4 x0 = a1raw[2 * it + 0], x1 = a1raw[2 * it + 1];
        float xs[8] = {x0.x, x0.y, x0.z, x0.w, x1.x, x1.y, x1.z, x1.w};
        half8 hi, lo;
        #pragma unroll
        for (int j = 0; j < 8; ++j) {
            _Float16 h = (_Float16)xs[j];
            hi[j] = h;
            lo[j] = (_Float16)(xs[j] - (float)h);
        }
        *((half8*)&Ahi[(g * 64 + lane) * 8]) = hi;
        *((half8*)&Alo[(g * 64 + lane) * 8]) = lo;
    }
    __syncthreads();

    // ---- compute half 1 ----
    COMPUTE_HALF(1)
#undef COMPUTE_HALF

    // ---- layer-2 fold (re-indexed for 8 waves x 2 nt) ----
    float b1v[2], w2v[2];
    #pragma unroll
    for (int ntl = 0; ntl < 2; ++ntl) {
        int n = (w * 2 + ntl) * 16 + l16;
        b1v[ntl] = b1[n];
        w2v[ntl] = W2[n];
    }
    #pragma unroll
    for (int mt = 0; mt < 4; ++mt) {
        #pragma unroll
        for (int r = 0; r < 4; ++r) {
            float p = 0.f;
            #pragma unroll
            for (int ntl = 0; ntl < 2; ++ntl) {
                float h = fmaxf(acc[mt][ntl][r] + b1v[ntl], 0.f);
                p = fmaf(h, w2v[ntl], p);
            }
            p += __shfl_xor(p, 1);
            p += __shfl_xor(p, 2);
            p += __shfl_xor(p, 4);
            p += __shfl_xor(p, 8);
            if (l16 == 0) SP[(mt * 16 + quad * 4 + r) * 8 + w] = p;
        }
    }
    __syncthreads();

    // ---- inverse-distance softmax over L=64 (wave 0) ----
    if (t < LL) {
        float s = SP[8 * t + 0] + SP[8 * t + 1] + SP[8 * t + 2] + SP[8 * t + 3]
                + SP[8 * t + 4] + SP[8 * t + 5] + SP[8 * t + 6] + SP[8 * t + 7] + b2[0];
        float score = fmaxf(s, 0.f);
        float dx = src_locs[(b * LL + t) * 2 + 0] - tar_locs[b * 2 + 0];
        float dy = src_locs[(b * LL + t) * 2 + 1] - tar_locs[b * 2 + 1];
        float inv = 1.0f / sqrtf(dx * dx + dy * dy);
        float logit = score * inv;
        float m = logit;
        #pragma unroll
        for (int o = 32; o > 0; o >>= 1) m = fmaxf(m, __shfl_xor(m, o));
        float e = __expf(logit - m);
        float se = e;
        #pragma unroll
        for (int o = 32; o > 0; o >>= 1) se += __shfl_xor(se, o);
        wbuf[t] = e / se;
    }
    __syncthreads();

    // ---- weighted sum over stations (8 waves x 8 rows each) ----
    {
        const float4* Xg4 = (const float4*)Xg;
        floatx4 o = {0.f, 0.f, 0.f, 0.f};
        #pragma unroll
        for (int lr = 0; lr < 8; ++lr) {
            int l = w * 8 + lr;
            float wl = wbuf[l];
            float4 x = Xg4[l * 64 + lane];
            o[0] = fmaf(x.x, wl, o[0]);
            o[1] = fmaf(x.y, wl, o[1]);
            o[2] = fmaf(x.z, wl, o[2]);
            o[3] = fmaf(x.w, wl, o[3]);
        }
        *((floatx4*)&red[w * FF + lane * 4]) = o;
    }
    __syncthreads();
    if (t < FF) {
        float o = red[0 * FF + t] + red[1 * FF + t] + red[2 * FF + t] + red[3 * FF + t]
                + red[4 * FF + t] + red[5 * FF + t] + red[6 * FF + t] + red[7 * FF + t];
        out[(size_t)bs * FF + t] = o;
    }
}

extern "C" void kernel_launch(void* const* d_in, const int* in_sizes, int n_in,
                              void* d_out, int out_size, void* d_ws, size_t ws_size,
                              hipStream_t stream) {
    const float* features = (const float*)d_in[0];
    const float* src_locs = (const float*)d_in[1];
    const float* tar_locs = (const float*)d_in[2];
    const float* W1       = (const float*)d_in[3];
    const float* b1       = (const float*)d_in[4];
    const float* W2       = (const float*)d_in[5];
    const float* b2       = (const float*)d_in[6];
    float* out = (float*)d_out;

    _Float16* whi = (_Float16*)d_ws;               // 128 KiB
    _Float16* wlo = whi + FF * FF;                 // 128 KiB

    prep_w<<<dim3(FF * FF / 256), dim3(256), 0, stream>>>(W1, whi, wlo);
    ida_mfma<<<dim3(BB * SS), dim3(512), 0, stream>>>(
        features, src_locs, tar_locs, whi, wlo, b1, W2, b2, out);
}

// Round 2
// 183.911 us; speedup vs baseline: 1.0357x; 1.0357x over previous
//
#include <hip/hip_runtime.h>
#include <hip/hip_fp16.h>
#include <math.h>

typedef _Float16 half8 __attribute__((ext_vector_type(8)));
typedef float floatx4 __attribute__((ext_vector_type(4)));

#define BB 32
#define SS 48
#define LL 64
#define FF 256

// ---- prep (proven): W1 -> fp16 hi/lo MFMA-B fragment order ----
//   flat = ((kt*16 + nt)*64 + lane)*8 + j ; element = W1[kt*32+(lane>>4)*8+j][nt*16+(lane&15)]
__global__ __launch_bounds__(256) void prep_w(const float* __restrict__ W1,
                                              _Float16* __restrict__ whi,
                                              _Float16* __restrict__ wlo) {
    int idx = blockIdx.x * 256 + threadIdx.x;
    int j    = idx & 7;
    int lane = (idx >> 3) & 63;
    int nt   = (idx >> 9) & 15;
    int kt   = idx >> 13;
    int k = kt * 32 + ((lane >> 4) & 3) * 8 + j;
    int n = nt * 16 + (lane & 15);
    float x = W1[k * FF + n];
    _Float16 hi = (_Float16)x;
    _Float16 lo = (_Float16)(x - (float)hi);
    whi[idx] = hi;
    wlo[idx] = lo;
}

// ---- fused kernel: R1 skeleton + LDS-union + 3 blocks/CU + hoisted tail loads ----
// LDS: epilogue buffers alias the A-staging space (all transitions are
// barrier-separated). 32 KiB/block -> LDS allows 4; __launch_bounds__(512,6)
// caps regs at 85 (measured 76 unified in R1) -> 6 waves/SIMD = 3 blocks/CU.
__global__ __launch_bounds__(512, 6) void ida_mfma(
    const float* __restrict__ features,
    const float* __restrict__ src_locs,
    const float* __restrict__ tar_locs,
    const _Float16* __restrict__ whi,
    const _Float16* __restrict__ wlo,
    const float* __restrict__ b1,
    const float* __restrict__ W2,
    const float* __restrict__ b2,
    float* __restrict__ out)
{
    __shared__ __align__(16) unsigned char smem[32768];
    _Float16* Ahi = (_Float16*)smem;            // 16 KiB: [(mt*4+ktl)*64 + lane]*8
    _Float16* Alo = (_Float16*)(smem + 16384);  // 16 KiB
    // epilogue aliases (valid only after the post-compute barrier):
    float* SP   = (float*)smem;                 // [row][wave]  512 floats
    float* wbuf = SP + LL * 8;                  // 64 floats
    float* red  = wbuf + LL;                    // 2048 floats; total 10.25 KiB < 32 KiB

    const int t    = threadIdx.x;
    const int w    = t >> 6;         // wave 0..7 -> owns cols 32w..32w+31
    const int lane = t & 63;
    const int quad = lane >> 4;
    const int l16  = lane & 15;
    const int bs   = blockIdx.x;
    const int b    = bs / SS;

    const float* Xg = features + (size_t)bs * (LL * FF);

    // ---- hoist softmax-tail globals: issue at kernel start, hide under GEMM ----
    float inv_d = 0.f, b2v = 0.f;
    if (t < LL) {
        float dx = src_locs[(b * LL + t) * 2 + 0] - tar_locs[b * 2 + 0];
        float dy = src_locs[(b * LL + t) * 2 + 1] - tar_locs[b * 2 + 1];
        inv_d = 1.0f / sqrtf(dx * dx + dy * dy);
        b2v = b2[0];
    }

    floatx4 acc[4][2] = {};          // [mt][ntl] -> 32 AGPRs
    half8 bh[2], bl[2], nbh[2], nbl[2];

    // ---- stage half 0 (A0: global load + cvt + ds_write) ----
    // group g = it*8+w (0..15): row=(g>>2)*16+l16, kcol=(g&3)*32+quad*8
    #pragma unroll
    for (int it = 0; it < 2; ++it) {
        int g   = it * 8 + w;
        int row = (g >> 2) * 16 + l16;
        int kc  = (g & 3) * 32 + quad * 8;
        const float4* p = (const float4*)(Xg + row * FF + kc);
        float4 x0 = p[0], x1 = p[1];
        float xs[8] = {x0.x, x0.y, x0.z, x0.w, x1.x, x1.y, x1.z, x1.w};
        half8 hi, lo;
        #pragma unroll
        for (int j = 0; j < 8; ++j) {
            _Float16 h = (_Float16)xs[j];
            hi[j] = h;
            lo[j] = (_Float16)(xs[j] - (float)h);
        }
        *((half8*)&Ahi[(g * 64 + lane) * 8]) = hi;
        *((half8*)&Alo[(g * 64 + lane) * 8]) = lo;
    }

    // ---- issue A1 raw loads now; latency hides under half-0 compute ----
    float4 a1raw[4];
    #pragma unroll
    for (int it = 0; it < 2; ++it) {
        int g   = it * 8 + w;
        int row = (g >> 2) * 16 + l16;
        int kc  = (g & 3) * 32 + quad * 8;
        const float4* p = (const float4*)(Xg + row * FF + 128 + kc);
        a1raw[2 * it + 0] = p[0];
        a1raw[2 * it + 1] = p[1];
    }

    // ---- preload B fragments for half 0, ktl 0 ----
    #pragma unroll
    for (int ntl = 0; ntl < 2; ++ntl) {
        size_t off = ((size_t)(0 * 16 + (w * 2 + ntl)) * 64 + lane) * 8;
        bh[ntl] = *((const half8*)(whi + off));
        bl[ntl] = *((const half8*)(wlo + off));
    }

    __syncthreads();

    // ---- compute one K-half: per-ktl B prefetch + MFMA ----
#define COMPUTE_HALF(h)                                                          \
    _Pragma("unroll")                                                            \
    for (int ktl = 0; ktl < 4; ++ktl) {                                          \
        if (ktl < 3) {                                                           \
            _Pragma("unroll")                                                    \
            for (int ntl = 0; ntl < 2; ++ntl) {                                  \
                size_t off = ((size_t)(((h) * 4 + ktl + 1) * 16 + (w * 2 + ntl)) * 64 + lane) * 8; \
                nbh[ntl] = *((const half8*)(whi + off));                         \
                nbl[ntl] = *((const half8*)(wlo + off));                         \
            }                                                                    \
        }                                                                        \
        _Pragma("unroll")                                                        \
        for (int mt = 0; mt < 4; ++mt) {                                         \
            half8 ahi = *((half8*)&Ahi[((mt * 4 + ktl) * 64 + lane) * 8]);       \
            half8 alo = *((half8*)&Alo[((mt * 4 + ktl) * 64 + lane) * 8]);       \
            _Pragma("unroll")                                                    \
            for (int ntl = 0; ntl < 2; ++ntl) {                                  \
                acc[mt][ntl] = __builtin_amdgcn_mfma_f32_16x16x32_f16(ahi, bh[ntl], acc[mt][ntl], 0, 0, 0); \
                acc[mt][ntl] = __builtin_amdgcn_mfma_f32_16x16x32_f16(ahi, bl[ntl], acc[mt][ntl], 0, 0, 0); \
                acc[mt][ntl] = __builtin_amdgcn_mfma_f32_16x16x32_f16(alo, bh[ntl], acc[mt][ntl], 0, 0, 0); \
            }                                                                    \
        }                                                                        \
        if (ktl < 3) {                                                           \
            bh[0] = nbh[0]; bh[1] = nbh[1];                                      \
            bl[0] = nbl[0]; bl[1] = nbl[1];                                      \
        }                                                                        \
    }

    // ---- compute half 0 ----
    COMPUTE_HALF(0)

    // ---- preload B for half 1, ktl 0 (hides under stage1) ----
    #pragma unroll
    for (int ntl = 0; ntl < 2; ++ntl) {
        size_t off = ((size_t)(4 * 16 + (w * 2 + ntl)) * 64 + lane) * 8;
        bh[ntl] = *((const half8*)(whi + off));
        bl[ntl] = *((const half8*)(wlo + off));
    }

    __syncthreads();   // half-0 LDS reads complete before overwrite

    // ---- stage half 1 (cvt + ds_write only; a1raw long in flight) ----
    #pragma unroll
    for (int it = 0; it < 2; ++it) {
        int g = it * 8 + w;
        float4 x0 = a1raw[2 * it + 0], x1 = a1raw[2 * it + 1];
        float xs[8] = {x0.x, x0.y, x0.z, x0.w, x1.x, x1.y, x1.z, x1.w};
        half8 hi, lo;
        #pragma unroll
        for (int j = 0; j < 8; ++j) {
            _Float16 h = (_Float16)xs[j];
            hi[j] = h;
            lo[j] = (_Float16)(xs[j] - (float)h);
        }
        *((half8*)&Ahi[(g * 64 + lane) * 8]) = hi;
        *((half8*)&Alo[(g * 64 + lane) * 8]) = lo;
    }
    __syncthreads();

    // ---- compute half 1 ----
    COMPUTE_HALF(1)
#undef COMPUTE_HALF

    // ---- barrier: all GEMM LDS reads done before epilogue aliases A-space ----
    __syncthreads();

    // ---- layer-2 fold (8 waves x 2 nt) ----
    float b1v[2], w2v[2];
    #pragma unroll
    for (int ntl = 0; ntl < 2; ++ntl) {
        int n = (w * 2 + ntl) * 16 + l16;
        b1v[ntl] = b1[n];
        w2v[ntl] = W2[n];
    }
    #pragma unroll
    for (int mt = 0; mt < 4; ++mt) {
        #pragma unroll
        for (int r = 0; r < 4; ++r) {
            float p = 0.f;
            #pragma unroll
            for (int ntl = 0; ntl < 2; ++ntl) {
                float h = fmaxf(acc[mt][ntl][r] + b1v[ntl], 0.f);
                p = fmaf(h, w2v[ntl], p);
            }
            p += __shfl_xor(p, 1);
            p += __shfl_xor(p, 2);
            p += __shfl_xor(p, 4);
            p += __shfl_xor(p, 8);
            if (l16 == 0) SP[(mt * 16 + quad * 4 + r) * 8 + w] = p;
        }
    }
    __syncthreads();

    // ---- inverse-distance softmax over L=64 (wave 0; inv_d/b2v preloaded) ----
    if (t < LL) {
        float s = SP[8 * t + 0] + SP[8 * t + 1] + SP[8 * t + 2] + SP[8 * t + 3]
                + SP[8 * t + 4] + SP[8 * t + 5] + SP[8 * t + 6] + SP[8 * t + 7] + b2v;
        float score = fmaxf(s, 0.f);
        float logit = score * inv_d;
        float m = logit;
        #pragma unroll
        for (int o = 32; o > 0; o >>= 1) m = fmaxf(m, __shfl_xor(m, o));
        float e = __expf(logit - m);
        float se = e;
        #pragma unroll
        for (int o = 32; o > 0; o >>= 1) se += __shfl_xor(se, o);
        wbuf[t] = e / se;
    }
    __syncthreads();

    // ---- weighted sum over stations (8 waves x 8 rows each) ----
    {
        const float4* Xg4 = (const float4*)Xg;
        floatx4 o = {0.f, 0.f, 0.f, 0.f};
        #pragma unroll
        for (int lr = 0; lr < 8; ++lr) {
            int l = w * 8 + lr;
            float wl = wbuf[l];
            float4 x = Xg4[l * 64 + lane];
            o[0] = fmaf(x.x, wl, o[0]);
            o[1] = fmaf(x.y, wl, o[1]);
            o[2] = fmaf(x.z, wl, o[2]);
            o[3] = fmaf(x.w, wl, o[3]);
        }
        *((floatx4*)&red[w * FF + lane * 4]) = o;
    }
    __syncthreads();
    if (t < FF) {
        float o = red[0 * FF + t] + red[1 * FF + t] + red[2 * FF + t] + red[3 * FF + t]
                + red[4 * FF + t] + red[5 * FF + t] + red[6 * FF + t] + red[7 * FF + t];
        out[(size_t)bs * FF + t] = o;
    }
}

extern "C" void kernel_launch(void* const* d_in, const int* in_sizes, int n_in,
                              void* d_out, int out_size, void* d_ws, size_t ws_size,
                              hipStream_t stream) {
    const float* features = (const float*)d_in[0];
    const float* src_locs = (const float*)d_in[1];
    const float* tar_locs = (const float*)d_in[2];
    const float* W1       = (const float*)d_in[3];
    const float* b1       = (const float*)d_in[4];
    const float* W2       = (const float*)d_in[5];
    const float* b2       = (const float*)d_in[6];
    float* out = (float*)d_out;

    _Float16* whi = (_Float16*)d_ws;               // 128 KiB
    _Float16* wlo = whi + FF * FF;                 // 128 KiB

    prep_w<<<dim3(FF * FF / 256), dim3(256), 0, stream>>>(W1, whi, wlo);
    ida_mfma<<<dim3(BB * SS), dim3(512), 0, stream>>>(
        features, src_locs, tar_locs, whi, wlo, b1, W2, b2, out);
}